// Round 6
// baseline (254.668 us; speedup 1.0000x reference)
//
#include <hip/hip_runtime.h>
#include <stdint.h>

#define HW 9216
#define CDIM 128
#define WIDTH 96
#define BATCH 2
#define SPLITS 32           // 32 key-splits -> 32 partial streams
#define KSPLIT 288          // keys per split; LDS = 288*256B = 72 KB (2 blocks/CU)
#define NKG 9               // 288 / 32 keys per key-group
#define QTILE 512           // q-rows per block (8 waves x 64q = 2 qsets of 32)
#define NQT (HW / QTILE)    // 18 q-tiles
#define NWG (NQT * SPLITS * BATCH)   // 1152 blocks, 2/CU -> 2.25 rounds

// Logits: w = dot * QSCALE, e = (e^w)^2 = exp(dot/(0.1*sqrt(128))).
// |dot|<=1 -> |w|<=0.442: packed Taylor-4 + square, rel err ~3e-4 (<< f16 noise).
#define QSCALE 0.44194173824159216f
// conf numerator: exp(2*mx) = exp2(mx * 2/ln2)
#define MXSCALE 2.8853900817779268f

typedef _Float16 half8 __attribute__((ext_vector_type(8)));
typedef float f32x16 __attribute__((ext_vector_type(16)));
typedef float float2v __attribute__((ext_vector_type(2)));

// ---------------------------------------------------------------------------
// Kernel 1: L2-normalize over C, write fp16 [B][HW][C] (unchanged).
// ---------------------------------------------------------------------------
__global__ __launch_bounds__(256) void norm_kernel(const float* __restrict__ fL,
                                                   const float* __restrict__ fR,
                                                   _Float16* __restrict__ Qh,
                                                   _Float16* __restrict__ Kh)
{
    __shared__ float ssred[4][64];
    __shared__ _Float16 ot[64 * 130];   // +2 halves pad -> bank advance 1/row

    const float* src = (blockIdx.y == 0) ? fL : fR;
    _Float16* dst    = (blockIdx.y == 0) ? Qh : Kh;
    const float outScale = (blockIdx.y == 0) ? QSCALE : 1.0f;

    const int t = threadIdx.x;
    const int pos_l = t & 63, cg = t >> 6;            // 4 channel groups of 32
    const int pos0 = blockIdx.x * 64;                  // 64 | HW so no straddle
    const int b = pos0 / HW, pos_in = pos0 % HW + pos_l;

    const float* p = src + (size_t)b * CDIM * HW + pos_in;

    float v[32];
    float ss = 0.f;
    #pragma unroll
    for (int j = 0; j < 32; ++j) {
        v[j] = p[(size_t)(cg * 32 + j) * HW];
        ss += v[j] * v[j];
    }
    ssred[cg][pos_l] = ss;
    __syncthreads();
    float tot = ssred[0][pos_l] + ssred[1][pos_l] + ssred[2][pos_l] + ssred[3][pos_l];
    float scale = outScale / fmaxf(sqrtf(tot), 1e-6f);

    #pragma unroll
    for (int j = 0; j < 32; ++j)
        ot[pos_l * 130 + cg * 32 + j] = (_Float16)(v[j] * scale);
    __syncthreads();

    uint4* og = (uint4*)(dst + (size_t)(b * HW + pos0 % HW + 0) * CDIM);
    #pragma unroll
    for (int i = 0; i < 4; ++i) {
        int idx = i * 256 + t;            // 0..1023 dwordx4 slots
        int row = idx >> 4, chunk = idx & 15;
        og[idx] = *(const uint4*)&ot[row * 130 + chunk * 8];
    }
}

// ---------------------------------------------------------------------------
// Kernel 2: fused correlation + softmax-accumulate — persistent-K, 8 waves.
//   Round-5 finding: barrier-free vs barrier-heavy is NULL at 2 waves/SIMD
//   (LDS 72 KB -> 2 blocks/CU x 4 waves). The un-moved knob across 5 rounds
//   is steady-state waves/SIMD. This round: 512-thr blocks (8 waves x 64q),
//   same 72 KB persistent K -> 16 waves/CU = 4/SIMD, 2x round 5.
//   VGPR diet to fit the 128-reg cap of 4 waves/SIMD without spill:
//   E2[2][8] deferred fold (32 regs) replaced by per-kg incremental
//   AX2 += e*c0vec[p] (8 loop-invariant packed crow consts, 16 regs) +
//   L2/AY2/MX2; net -12 regs, same epilogue op count (fma swaps for add).
//   Verify in counters: WRITE_SIZE ~9.5-12 MB (round 5's spill was +16 MB).
//   XCD chunking: NWG 1152 = 8 x 144; each XCD owns sb in [xcd*8, xcd*8+8):
//   8 K-splits (576 KB) + one batch's Q slices, L2-resident.
// ---------------------------------------------------------------------------
__global__ __launch_bounds__(512, 4) void attn_kernel(const _Float16* __restrict__ Qh,
                                                      const _Float16* __restrict__ Kh,
                                                      float4* __restrict__ part)
{
    __shared__ __align__(16) _Float16 Ks[KSPLIT * 128];   // 72 KB, staged once

    // bijective XCD swizzle (NWG % 8 == 0): xcd = wg & 7 gets chunk of 144
    const int wg0 = blockIdx.x;
    const int nid = (wg0 & 7) * (NWG / 8) + (wg0 >> 3);
    const int qt = nid % NQT;
    const int sb = nid / NQT;            // 0..63, 8 consecutive per XCD
    const int split = sb & 31;
    const int b = sb >> 5;

    const int t = threadIdx.x;
    const int lane = t & 63, wave = t >> 6;        // 8 waves
    const int lane31 = lane & 31, hi = lane >> 5;
    const int ln15 = lane & 15, qd = lane >> 4;

    const char* kp0 = (const char*)(Kh + (size_t)b * HW * CDIM) +
                      (size_t)(split * KSPLIT) * (CDIM * 2);

    // ---- stage the whole K-split: wave stages rows [wave*36, wave*36+36) ----
    // 9 DMAs x (4 rows x 256B). LDS dest linear (instr adds lane*16B);
    // source 16B-chunk XOR-swizzled: LDS[r][c] = K[r][c ^ (r&15)] ->
    // conflict-free fragment reads. (r&15) has period 4 in the DMA index i,
    // so 4 base voffsets + i*1024 reconstruct r*256 + swz for all 9.
    {
        int voff4[4];
        #pragma unroll
        for (int i = 0; i < 4; ++i) {
            int r = wave * 36 + i * 4 + qd;
            voff4[i] = r * 256 + ((ln15 ^ (r & 15)) << 4) - i * 1024;
        }
        _Float16* db = &Ks[wave * (36 * 128)];
        #pragma unroll
        for (int i = 0; i < 9; ++i)
            __builtin_amdgcn_global_load_lds(
                (const __attribute__((address_space(1))) uint32_t*)(kp0 + voff4[i & 3] + i * 1024),
                (__attribute__((address_space(3))) uint32_t*)(db + i * 512),
                16, 0, 0);
    }

    // ---- Q fragments, 2 qsets (B-operand): col = lane31 = q-row, k = hi*8+j ----
    half8 qf[2][8];
    {
        #pragma unroll
        for (int s = 0; s < 2; ++s) {
            const char* qb = (const char*)(Qh +
                ((size_t)(b * HW + qt * QTILE + wave * 64 + s * 32 + lane31)) * CDIM);
            #pragma unroll
            for (int kc = 0; kc < 8; ++kc)
                qf[s][kc] = *(const half8*)(qb + kc * 32 + hi * 16);
        }
    }

    // K-frag (A-operand) LDS byte offsets for kg=0: row = lane31, chunk
    // (kc*2+hi) un-swizzled via ^ln15 (row&15 == ln15). kg adds kg*8192.
    int rdoff[8];
    #pragma unroll
    for (int kc = 0; kc < 8; ++kc)
        rdoff[kc] = (lane31 << 8) + ((((kc << 1) | hi) ^ ln15) << 4);

    // coordinates: key = split*288 + kg*32 + crow + 4hi; 288 % 96 == 0 ->
    // x = 32*(kg%3) + crow + 4hi (never wraps), y = split*3 + kg/3.
    const float ysp = (float)(split * 3);

    // crow weights for acc pair (2p, 2p+1): {c0, c0+1}, c0 = (2p&3) + 8*(2p>>2)
    float2v c0v[8];
    #pragma unroll
    for (int p = 0; p < 8; ++p) {
        const float c0 = (float)(((2 * p) & 3) + 8 * ((2 * p) >> 2)); // 0,2,8,...,26
        c0v[p].x = c0; c0v[p].y = c0 + 1.0f;
    }

    // per-qset accumulators (packed over adjacent crows)
    float2v L2[2], AX2[2], AY2[2], MX2[2];
    #pragma unroll
    for (int s = 0; s < 2; ++s) {
        L2[s] = (float2v)0.f; AX2[s] = (float2v)0.f; AY2[s] = (float2v)0.f;
        MX2[s] = (float2v)(-1.0e30f);
    }

    const char* ksb = (const char*)&Ks[0];
    const float2v C4 = (float2v)(1.0f / 24.0f), C3 = (float2v)(1.0f / 6.0f),
                  C2 = (float2v)0.5f, C1 = (float2v)1.0f;

    __syncthreads();   // K fully staged (single vmcnt(0) drain of the run)

    // ---- free-running main loop: 9 independent key-groups, no sync ----
    #pragma unroll
    for (int kg = 0; kg < NKG; ++kg) {
        f32x16 acc[2];
        #pragma unroll
        for (int kc = 0; kc < 8; ++kc) {
            half8 kf = *(const half8*)(ksb + kg * 8192 + rdoff[kc]);
            #pragma unroll
            for (int s = 0; s < 2; ++s)
                acc[s] = __builtin_amdgcn_mfma_f32_32x32x16_f16(
                    kf, qf[s][kc], (kc == 0) ? (f32x16)0.f : acc[s], 0, 0, 0);
        }

        const float xb = (float)(32 * (kg % 3));       // inline const (0/32/64)
        const float yk = ysp + (float)(kg / 3);
        #pragma unroll
        for (int s = 0; s < 2; ++s) {
            float2v lt2;
            #pragma unroll
            for (int p = 0; p < 8; ++p) {
                float2v w;
                w.x = acc[s][2 * p];
                w.y = acc[s][2 * p + 1];
                MX2[s] = __builtin_elementwise_max(MX2[s], w);
                float2v h = w * C4 + C3;          // e^w, Taylor-4 on |w|<=0.442
                h = h * w + C2;
                h = h * w + C1;
                h = h * w + C1;
                float2v e = h * h;                // square back to full range
                AX2[s] += e * c0v[p];             // crow weight, incremental
                lt2 = (p == 0) ? e : (lt2 + e);
            }
            L2[s]  += lt2;
            AX2[s] += lt2 * (float2v)xb;
            AY2[s] += lt2 * (float2v)yk;
        }
    }

    // ---- per-qset fold + hi/lo combine + store ----
    #pragma unroll
    for (int s = 0; s < 2; ++s) {
        float l  = L2[s].x + L2[s].y;
        float ax = AX2[s].x + AX2[s].y + (float)(4 * hi) * l;
        float ay = AY2[s].x + AY2[s].y;
        float mx = fmaxf(MX2[s].x, MX2[s].y);

        l  += __shfl_xor(l, 32, 64);
        ax += __shfl_xor(ax, 32, 64);
        ay += __shfl_xor(ay, 32, 64);
        mx  = fmaxf(mx, __shfl_xor(mx, 32, 64));

        if (hi == 0) {
            int row = qt * QTILE + wave * 64 + s * 32 + lane31;
            part[(size_t)split * (BATCH * HW) + b * HW + row] =
                make_float4(l, ax, ay, __builtin_amdgcn_exp2f(mx * MXSCALE));
        }
    }
}

// ---------------------------------------------------------------------------
// Kernel 3: combine 32 partials per query row, write flow + conf
// ---------------------------------------------------------------------------
__global__ __launch_bounds__(256) void combine_kernel(const float4* __restrict__ part,
                                                      float* __restrict__ out)
{
    int tid = blockIdx.x * 256 + threadIdx.x;   // 0 .. B*HW-1 (grid sized exactly)
    int b = tid / HW, pos = tid % HW;
    float l = 0.f, ax = 0.f, ay = 0.f, mx = 0.f;
    #pragma unroll
    for (int s = 0; s < SPLITS; ++s) {
        float4 v = part[(size_t)s * (BATCH * HW) + tid];   // coalesced
        l += v.x; ax += v.y; ay += v.z; mx = fmaxf(mx, v.w);
    }
    float inv = 1.0f / l;
    int x = pos % WIDTH, y = pos / WIDTH;
    out[(size_t)b * 2 * HW + pos]           = ax * inv - (float)x;
    out[(size_t)b * 2 * HW + HW + pos]      = ay * inv - (float)y;
    out[(size_t)BATCH * 2 * HW + (size_t)b * HW + pos] = mx * inv;
}

// ---------------------------------------------------------------------------
extern "C" void kernel_launch(void* const* d_in, const int* in_sizes, int n_in,
                              void* d_out, int out_size, void* d_ws, size_t ws_size,
                              hipStream_t stream)
{
    const float* fL = (const float*)d_in[0];
    const float* fR = (const float*)d_in[1];
    float* out = (float*)d_out;

    char* ws = (char*)d_ws;
    const size_t QH_BYTES = (size_t)BATCH * HW * CDIM * sizeof(_Float16);  // 4.72 MB
    _Float16* Qh  = (_Float16*)ws;
    _Float16* Kh  = (_Float16*)(ws + QH_BYTES);
    float4*   part = (float4*)(ws + 2 * QH_BYTES);                         // 9.44 MB

    norm_kernel<<<dim3((BATCH * HW) / 64, 2), 256, 0, stream>>>(fL, fR, Qh, Kh);
    attn_kernel<<<dim3(NWG), 512, 0, stream>>>(Qh, Kh, part);
    combine_kernel<<<dim3((BATCH * HW) / 256), 256, 0, stream>>>(part, out);
}

// Round 7
// 137.195 us; speedup vs baseline: 1.8562x; 1.8562x over previous
//
#include <hip/hip_runtime.h>
#include <stdint.h>

#define HW 9216
#define CDIM 128
#define WIDTH 96
#define BATCH 2
#define SPLITS 48           // 48 key-splits -> 48 partial streams
#define KSPLIT 192          // keys per split; LDS = 192*256B = 48 KB -> 3 blocks/CU
#define NKG 6               // 192 / 32 keys per key-group
#define QTILE 128           // q-rows per block (4 waves x 32q)
#define NQT (HW / QTILE)    // 72 q-tiles
#define NWG (NQT * SPLITS * BATCH)   // 6912 blocks = 8 x 864

// Logits: w = dot * QSCALE, e = (e^w)^2 = exp(dot/(0.1*sqrt(128))).
// |dot|<=1 -> |w|<=0.442: packed Taylor-4 + square, rel err ~3e-4 (<< f16 noise).
#define QSCALE 0.44194173824159216f
// conf numerator: exp(2*mx) = exp2(mx * 2/ln2)
#define MXSCALE 2.8853900817779268f

typedef _Float16 half8 __attribute__((ext_vector_type(8)));
typedef float f32x16 __attribute__((ext_vector_type(16)));
typedef float float2v __attribute__((ext_vector_type(2)));

// ---------------------------------------------------------------------------
// Kernel 1: L2-normalize over C, write fp16 [B][HW][C] (unchanged).
// ---------------------------------------------------------------------------
__global__ __launch_bounds__(256) void norm_kernel(const float* __restrict__ fL,
                                                   const float* __restrict__ fR,
                                                   _Float16* __restrict__ Qh,
                                                   _Float16* __restrict__ Kh)
{
    __shared__ float ssred[4][64];
    __shared__ _Float16 ot[64 * 130];   // +2 halves pad -> bank advance 1/row

    const float* src = (blockIdx.y == 0) ? fL : fR;
    _Float16* dst    = (blockIdx.y == 0) ? Qh : Kh;
    const float outScale = (blockIdx.y == 0) ? QSCALE : 1.0f;

    const int t = threadIdx.x;
    const int pos_l = t & 63, cg = t >> 6;            // 4 channel groups of 32
    const int pos0 = blockIdx.x * 64;                  // 64 | HW so no straddle
    const int b = pos0 / HW, pos_in = pos0 % HW + pos_l;

    const float* p = src + (size_t)b * CDIM * HW + pos_in;

    float v[32];
    float ss = 0.f;
    #pragma unroll
    for (int j = 0; j < 32; ++j) {
        v[j] = p[(size_t)(cg * 32 + j) * HW];
        ss += v[j] * v[j];
    }
    ssred[cg][pos_l] = ss;
    __syncthreads();
    float tot = ssred[0][pos_l] + ssred[1][pos_l] + ssred[2][pos_l] + ssred[3][pos_l];
    float scale = outScale / fmaxf(sqrtf(tot), 1e-6f);

    #pragma unroll
    for (int j = 0; j < 32; ++j)
        ot[pos_l * 130 + cg * 32 + j] = (_Float16)(v[j] * scale);
    __syncthreads();

    uint4* og = (uint4*)(dst + (size_t)(b * HW + pos0 % HW + 0) * CDIM);
    #pragma unroll
    for (int i = 0; i < 4; ++i) {
        int idx = i * 256 + t;            // 0..1023 dwordx4 slots
        int row = idx >> 4, chunk = idx & 15;
        og[idx] = *(const uint4*)&ot[row * 130 + chunk * 8];
    }
}

// ---------------------------------------------------------------------------
// Kernel 2: fused correlation + softmax-accumulate — persistent-K, 1 qset,
// packed-asm epilogue, wave-staggered key-groups.
//   Diagnosis r0-r6: matrix-pipe per-SIMD busy floor is 17.5 us (MfmaUtil 26%
//   @72us matches); it starves because (a) ~2 waves/SIMD, (b) waves convoy
//   through identical phases, (c) hipcc scalarizes the float2v epilogue
//   (VALUBusy 33% matches scalar count).
//   Fixes: (1) 1 qset/wave -> ~140 VGPR state -> launch_bounds(256,3), LDS
//   48 KB -> 3 blocks/CU = 3 waves/SIMD, 6912 small blocks. (2) epilogue in
//   inline-asm v_pk_fma/mul/add_f32 (VOP3P; no pk_max exists -> scalar max).
//   (3) two independent 4-MFMA chains + per-wave kg stagger (wave w starts
//   at kg=w) -> block's 4 waves permanently anti-phased; setprio(1) around
//   MFMA gets role diversity (T5 regime).
//   Spill check (r2/r6 lessons): WRITE_SIZE must be ~16 MB (part 14.2).
// ---------------------------------------------------------------------------
__global__ __launch_bounds__(256, 3) void attn_kernel(const _Float16* __restrict__ Qh,
                                                      const _Float16* __restrict__ Kh,
                                                      float4* __restrict__ part)
{
    __shared__ __align__(16) _Float16 Ks[KSPLIT * 128];   // 48 KB, staged once

    // bijective XCD swizzle (NWG % 8 == 0): xcd = wg & 7 gets chunk of 864
    const int wg0 = blockIdx.x;
    const int nid = (wg0 & 7) * (NWG / 8) + (wg0 >> 3);
    const int qt = nid % NQT;                  // qt fastest: K-split stays L2-hot
    const int sb = nid / NQT;                  // 0..95
    const int split = sb % SPLITS;
    const int b = sb / SPLITS;

    const int t = threadIdx.x;
    const int lane = t & 63, wave = t >> 6;        // 4 waves
    const int lane31 = lane & 31, hi = lane >> 5;
    const int ln15 = lane & 15, qd = lane >> 4;

    const char* kp0 = (const char*)(Kh + (size_t)b * HW * CDIM) +
                      (size_t)(split * KSPLIT) * (CDIM * 2);

    // ---- stage the whole K-split: wave stages rows [wave*48, wave*48+48) ----
    // 12 DMAs x (4 rows x 256B). LDS dest linear; source 16B-chunk
    // XOR-swizzled: LDS[r][c] = K[r][c ^ (r&15)]. wave*48 % 16 == 0, so
    // (r&15) has period 4 in DMA index i: 4 base voffsets + i*1024.
    {
        int voff4[4];
        #pragma unroll
        for (int i = 0; i < 4; ++i) {
            int r = wave * 48 + i * 4 + qd;
            voff4[i] = r * 256 + ((ln15 ^ (r & 15)) << 4) - i * 1024;
        }
        _Float16* db = &Ks[wave * (48 * 128)];
        #pragma unroll
        for (int i = 0; i < 12; ++i)
            __builtin_amdgcn_global_load_lds(
                (const __attribute__((address_space(1))) uint32_t*)(kp0 + voff4[i & 3] + i * 1024),
                (__attribute__((address_space(3))) uint32_t*)(db + i * 512),
                16, 0, 0);
    }

    // ---- Q fragments, 1 qset (B-operand): col = lane31 = q-row, k = hi*8+j ----
    half8 qf[8];
    {
        const char* qb = (const char*)(Qh +
            ((size_t)(b * HW + qt * QTILE + wave * 32 + lane31)) * CDIM);
        #pragma unroll
        for (int kc = 0; kc < 8; ++kc)
            qf[kc] = *(const half8*)(qb + kc * 32 + hi * 16);
    }

    // K-frag (A-operand) LDS byte offsets: row = lane31, chunk (kc*2+hi)
    // un-swizzled via ^ln15. kg adds kg*8192.
    int rdoff[8];
    #pragma unroll
    for (int kc = 0; kc < 8; ++kc)
        rdoff[kc] = (lane31 << 8) + ((((kc << 1) | hi) ^ ln15) << 4);

    // ---- staggered key-group tables: wave w visits kg = (w+i) % 6 ----
    // key = split*192 + kg*32 + crow + 4hi; split*192 % 96 == 0 ->
    // x = 32*(kg%3) + crow + 4hi (never wraps), y = split*2 + kg/3.
    int kgo[NKG];
    float xkt[NKG], ykt[NKG];
    #pragma unroll
    for (int i = 0; i < NKG; ++i) {
        int k = wave + i;
        if (k >= NKG) k -= NKG;
        kgo[i] = k * 8192;
        int k3 = (k >= 3) ? (k - 3) : k;
        xkt[i] = (float)(32 * k3);
        ykt[i] = (float)(split * 2 + ((k >= 3) ? 1 : 0));
    }

    // accumulators (packed pairs over adjacent crows; E2 fold deferred)
    float2v E2[8];
    #pragma unroll
    for (int p = 0; p < 8; ++p) E2[p] = (float2v)0.f;
    float2v mx2 = (float2v)(-1.0e30f);
    float2v axb2 = (float2v)0.f, ay2 = (float2v)0.f;

    const char* ksb = (const char*)&Ks[0];
    const float2v C4 = (float2v)(1.0f / 24.0f), C3 = (float2v)(1.0f / 6.0f),
                  C2 = (float2v)0.5f, C1 = (float2v)1.0f;

    __syncthreads();   // K fully staged (single vmcnt(0) drain of the run)

    // ---- free-running main loop: 6 independent key-groups, wave-staggered ----
    #pragma unroll
    for (int i = 0; i < NKG; ++i) {
        const char* kb = ksb + kgo[i];
        f32x16 accA, accB;                 // two independent 4-deep chains
        __builtin_amdgcn_s_setprio(1);
        #pragma unroll
        for (int kc = 0; kc < 4; ++kc) {
            half8 kfA = *(const half8*)(kb + rdoff[kc]);
            half8 kfB = *(const half8*)(kb + rdoff[kc + 4]);
            accA = __builtin_amdgcn_mfma_f32_32x32x16_f16(
                kfA, qf[kc], (kc == 0) ? (f32x16)0.f : accA, 0, 0, 0);
            accB = __builtin_amdgcn_mfma_f32_32x32x16_f16(
                kfB, qf[kc + 4], (kc == 0) ? (f32x16)0.f : accB, 0, 0, 0);
        }
        __builtin_amdgcn_s_setprio(0);

        // ---- packed epilogue: v_pk_* asm (hipcc scalarizes float2v math) ----
        float2v lt;
        #pragma unroll
        for (int p = 0; p < 8; ++p) {
            float2v w;
            w.x = accA[2 * p] + accB[2 * p];
            w.y = accA[2 * p + 1] + accB[2 * p + 1];
            mx2.x = fmaxf(mx2.x, w.x);               // no v_pk_max_f32: scalar
            mx2.y = fmaxf(mx2.y, w.y);
            float2v h, e;
            asm("v_pk_fma_f32 %0, %1, %2, %3" : "=v"(h) : "v"(w), "v"(C4), "v"(C3));
            asm("v_pk_fma_f32 %0, %0, %1, %2" : "+v"(h) : "v"(w), "v"(C2));
            asm("v_pk_fma_f32 %0, %0, %1, %2" : "+v"(h) : "v"(w), "v"(C1));
            asm("v_pk_fma_f32 %0, %0, %1, %2" : "+v"(h) : "v"(w), "v"(C1));
            asm("v_pk_mul_f32 %0, %1, %1" : "=v"(e) : "v"(h));   // e = (e^w)^2 arg: h^2
            asm("v_pk_add_f32 %0, %0, %1" : "+v"(E2[p]) : "v"(e));
            if (p == 0) lt = e;
            else asm("v_pk_add_f32 %0, %0, %1" : "+v"(lt) : "v"(e));
        }
        float2v xb2, yk2;
        xb2.x = xkt[i]; xb2.y = xkt[i];
        yk2.x = ykt[i]; yk2.y = ykt[i];
        asm("v_pk_fma_f32 %0, %1, %2, %0" : "+v"(axb2) : "v"(lt), "v"(xb2));
        asm("v_pk_fma_f32 %0, %1, %2, %0" : "+v"(ay2)  : "v"(lt), "v"(yk2));
    }

    // ---- per-lane fold: apply compile-time crow weights once ----
    float l = 0.f, axc = 0.f;
    #pragma unroll
    for (int p = 0; p < 8; ++p) {
        const float c0 = (float)(((2 * p) & 3) + 8 * ((2 * p) >> 2)); // 0,2,8,...,26
        l   += E2[p].x + E2[p].y;
        axc += c0 * E2[p].x + (c0 + 1.0f) * E2[p].y;
    }
    float ax = axc + (float)(4 * hi) * l + axb2.x + axb2.y;
    float ay = ay2.x + ay2.y;
    float mx = fmaxf(mx2.x, mx2.y);

    // combine hi/lo key-halves (lanes l and l+32 share q = lane31)
    l  += __shfl_xor(l, 32, 64);
    ax += __shfl_xor(ax, 32, 64);
    ay += __shfl_xor(ay, 32, 64);
    mx  = fmaxf(mx, __shfl_xor(mx, 32, 64));

    if (hi == 0) {
        int row = qt * QTILE + wave * 32 + lane31;
        part[(size_t)split * (BATCH * HW) + b * HW + row] =
            make_float4(l, ax, ay, __builtin_amdgcn_exp2f(mx * MXSCALE));
    }
}

// ---------------------------------------------------------------------------
// Kernel 3: combine 48 partials per query row, write flow + conf
// ---------------------------------------------------------------------------
__global__ __launch_bounds__(256) void combine_kernel(const float4* __restrict__ part,
                                                      float* __restrict__ out)
{
    int tid = blockIdx.x * 256 + threadIdx.x;   // 0 .. B*HW-1 (grid sized exactly)
    int b = tid / HW, pos = tid % HW;
    float l = 0.f, ax = 0.f, ay = 0.f, mx = 0.f;
    #pragma unroll
    for (int s = 0; s < SPLITS; ++s) {
        float4 v = part[(size_t)s * (BATCH * HW) + tid];   // coalesced
        l += v.x; ax += v.y; ay += v.z; mx = fmaxf(mx, v.w);
    }
    float inv = 1.0f / l;
    int x = pos % WIDTH, y = pos / WIDTH;
    out[(size_t)b * 2 * HW + pos]           = ax * inv - (float)x;
    out[(size_t)b * 2 * HW + HW + pos]      = ay * inv - (float)y;
    out[(size_t)BATCH * 2 * HW + (size_t)b * HW + pos] = mx * inv;
}

// ---------------------------------------------------------------------------
extern "C" void kernel_launch(void* const* d_in, const int* in_sizes, int n_in,
                              void* d_out, int out_size, void* d_ws, size_t ws_size,
                              hipStream_t stream)
{
    const float* fL = (const float*)d_in[0];
    const float* fR = (const float*)d_in[1];
    float* out = (float*)d_out;

    char* ws = (char*)d_ws;
    const size_t QH_BYTES = (size_t)BATCH * HW * CDIM * sizeof(_Float16);  // 4.72 MB
    _Float16* Qh  = (_Float16*)ws;
    _Float16* Kh  = (_Float16*)(ws + QH_BYTES);
    float4*   part = (float4*)(ws + 2 * QH_BYTES);                         // 14.16 MB

    norm_kernel<<<dim3((BATCH * HW) / 64, 2), 256, 0, stream>>>(fL, fR, Qh, Kh);
    attn_kernel<<<dim3(NWG), 256, 0, stream>>>(Qh, Kh, part);
    combine_kernel<<<dim3((BATCH * HW) / 256), 256, 0, stream>>>(part, out);
}